// Round 2
// 358.186 us; speedup vs baseline: 1.0496x; 1.0496x over previous
//
#include <hip/hip_runtime.h>

// CTC batch cost forward, B=256, T=256, C=1000, L=64, S=129, blank=999.
// ROUND 8: FUSED single kernel (retry of R7 with the risky part removed).
// One 256-thread block per batch row b.
//   Waves 1..3 (producers): scattered 4B gathers p[lab]/p[blank] from y_pred,
//     REG-STAGED (fully-unrolled load-all -> store-all, ~22 outstanding loads
//     per wave) into LDS. No global_load_lds: R7 derived its LDS address from
//     threadIdx.x>>6 which is not provably wave-uniform -> suspected fault.
//   Wave 0 (consumer): linear-domain scaled-CTC recursion (identical FP op
//     sequence to the R6 kernel that benched absmax 0.0), consuming 64-row
//     chunks one __syncthreads() behind the producers.
// Scan latency (~1.4us/chunk) hides fully under the BW-bound gather
// (~6.5us/chunk; machine floor ~27us total on scattered 64B-line fetches).

#define T_    256
#define C_    1000
#define L_    64
#define BLANK 999       // C-1
#define EPSF  (1e-7f)
#define RS    68        // LDS row stride (floats): [blank, lab0..lab63, pad x3]
#define CHUNK 64        // rows per pipeline stage (4 stages)

__global__ __launch_bounds__(256)
void ctc_fused_kernel(const int* __restrict__ y_true,
                      const float* __restrict__ y_pred,
                      float* __restrict__ out) {
    __shared__ float sb[T_ * RS];                 // 69632 B, 1 block/CU

    const int wave = threadIdx.x >> 6;            // 0..3
    const int lane = threadIdx.x & 63;
    const int b    = blockIdx.x;

    const int lab = y_true[b * L_ + lane];        // coalesced, cache-hot
    const float* __restrict__ base = y_pred + (size_t)b * T_ * C_;

    // ---- chunk 0: all 4 waves gather rows 0..63 (16 rows each) ----
    {
        float v0[16];
        #pragma unroll
        for (int i = 0; i < 16; ++i)              // cluster 16 loads in flight
            v0[i] = base[(size_t)(wave + 4 * i) * C_ + lab];
        #pragma unroll
        for (int i = 0; i < 16; ++i)
            sb[(wave + 4 * i) * RS + 1 + lane] = v0[i];
        if (wave == 0)                            // blanks rows 0..63
            sb[lane * RS] = base[(size_t)lane * C_ + BLANK];
    }
    __syncthreads();

    // ---- scan state (wave 0) ----
    const int labm1 = __shfl_up(lab, 1, 64);
    const bool allow = (lane > 0) && (lab != labm1);

    // lane i holds A[2i] (aE), A[2i+1] (aO); lane 63 also A[128] (aL).
    float aE = 0.f, aO = 0.f, aL = 0.f, lsum = 0.f;
    float rB[4], rL[4];                           // 4-deep LDS read ring

    for (int k = 0; k < 4; ++k) {
        if (wave == 0) {
            // -------- consume chunk k: rows [tA, tB) --------
            const int tA = (k == 0) ? 1 : k * CHUNK;
            const int tB = k * CHUNK + CHUNK;
            if (k == 0) {
                aE = (lane == 0) ? sb[0] + EPSF : 0.f;
                aO = (lane == 0) ? sb[1] + EPSF : 0.f;
            }
            #pragma unroll
            for (int q = 0; q < 4; ++q) {         // ring init (chunk-local)
                rB[q] = sb[(tA + q) * RS] + EPSF;             // broadcast
                rL[q] = sb[(tA + q) * RS + 1 + lane] + EPSF;  // 2-way alias: free
            }
            for (int t0 = tA; t0 < tB; t0 += 4) {
                #pragma unroll
                for (int j = 0; j < 4; ++j) {
                    const int t = t0 + j;
                    if (t >= tB) break;           // uniform (chunk-0 tail)
                    const float pB = rB[j], pL = rL[j];
                    const int tn = t + 4;
                    if (tn < tB) {                // never read past barrier
                        rB[j] = sb[tn * RS] + EPSF;
                        rL[j] = sb[tn * RS + 1 + lane] + EPSF;
                    }

                    float upO = __shfl_up(aO, 1, 64);     // A_old[2i-1]
                    if (lane == 0) upO = 0.f;

                    const float nE = (aE + upO) * pB;             // s=2i (blank)
                    const float sk = allow ? upO : 0.f;
                    const float nO = (aO + aE + sk) * pL;         // s=2i+1 (label)
                    const float nL = (aL + aO) * pB;              // s=128 (lane63)
                    aE = nE; aO = nO; aL = nL;

                    if ((t & 7) == 0) {           // renormalize every 8 steps
                        float m = fmaxf(fmaxf(aE, aO), aL);
                        #pragma unroll
                        for (int d = 1; d < 64; d <<= 1)
                            m = fmaxf(m, __shfl_xor(m, d, 64));
                        const float r = __builtin_amdgcn_rcpf(m);
                        aE *= r; aO *= r; aL *= r;
                        lsum += __logf(m);        // off the critical chain
                    }
                }
            }
        } else if (k < 3) {
            // ---- produce chunk k+1: rows [tC, tC+64), waves 1..3 ----
            const int tC = (k + 1) * CHUNK;
            const int r0 = wave - 1;              // 0..2, stride 3
            float v[22];                          // unroll-const indices only
            #pragma unroll
            for (int i = 0; i < 22; ++i) {
                const int r = r0 + 3 * i;
                if (r < CHUNK)                    // cluster ~22 loads in flight
                    v[i] = base[(size_t)(tC + r) * C_ + lab];
            }
            #pragma unroll
            for (int i = 0; i < 22; ++i) {
                const int r = r0 + 3 * i;
                if (r < CHUNK)
                    sb[(tC + r) * RS + 1 + lane] = v[i];
            }
            if (wave == 1)                        // blanks rows tC..tC+63
                sb[(tC + lane) * RS] = base[(size_t)(tC + lane) * C_ + BLANK];
        }
        __syncthreads();                          // chunk k+1 ready / k consumed
    }

    if (wave == 0 && lane == 63) {
        // loss = -( log(A[128] + A[127]) + sum of log scales )
        out[b] = -(__logf(aL + aO) + lsum);
    }
}

extern "C" void kernel_launch(void* const* d_in, const int* in_sizes, int n_in,
                              void* d_out, int out_size, void* d_ws, size_t ws_size,
                              hipStream_t stream) {
    const int*   y_true = (const int*)d_in[0];
    const float* y_pred = (const float*)d_in[1];
    float*       out    = (float*)d_out;
    (void)in_sizes; (void)n_in; (void)d_ws; (void)ws_size; (void)out_size;

    ctc_fused_kernel<<<dim3(256), dim3(256), 0, stream>>>(y_true, y_pred, out);
}